// Round 5
// baseline (452.153 us; speedup 1.0000x reference)
//
#include <hip/hip_runtime.h>
#include <cstdint>
#include <cstddef>

#define N_NODES 100000
#define D 128
#define R 4
#define NE 150000
#define LAYERS 2
#define NROWS (R * N_NODES)   // 400000
#define CAP 16                // max in-degree per (rel,dst); Poisson(1.5) -> P(>16) ~ 1e-12

typedef __attribute__((ext_vector_type(8))) short bf16x8;
typedef __attribute__((ext_vector_type(4))) float f32x4;
typedef __attribute__((ext_vector_type(4))) int i32x4;
typedef __attribute__((ext_vector_type(4))) unsigned short u16x4;

__device__ __forceinline__ unsigned short f2bf(float x) {
  union { float f; unsigned int u; } v; v.f = x;
  unsigned int u = v.u;
  return (unsigned short)((u + 0x7fffu + ((u >> 16) & 1u)) >> 16);  // RNE
}
__device__ __forceinline__ float bf2f(unsigned short u) {
  union { unsigned int i; float f; } v; v.i = ((unsigned int)u) << 16;
  return v.f;
}

// ---- count out-degree (int atomics); deg_i pre-zeroed ----
__global__ void count_kernel(const int* __restrict__ edges, int* __restrict__ deg_i) {
  int e = blockIdx.x * blockDim.x + threadIdx.x;
  int r = blockIdx.y;
  if (e >= NE) return;
  int src = edges[(size_t)(r * 2) * NE + e];
  atomicAdd(&deg_i[r * N_NODES + src], 1);
}

__global__ void sout_kernel(const int* __restrict__ deg_i, float* __restrict__ s_out) {
  int i = blockIdx.x * blockDim.x + threadIdx.x;
  if (i >= NROWS) return;
  s_out[i] = rsqrtf(fmaxf((float)deg_i[i], 1.0f));
}

// fill padded edge records {src, s_out[src]}; cursor counts in-degree as side effect.
// rec is pre-zeroed, so unwritten (pad) slots are {src=0, sc=0.0f}.
__global__ void fill_kernel(const int* __restrict__ edges, const float* __restrict__ s_out,
                            int* __restrict__ cursor, int2* __restrict__ rec) {
  int e = blockIdx.x * blockDim.x + threadIdx.x;
  int r = blockIdx.y;
  if (e >= NE) return;
  int src = edges[(size_t)(r * 2) * NE + e];
  int dst = edges[(size_t)(r * 2 + 1) * NE + e];
  float sc = s_out[r * N_NODES + src];
  int rowg = r * N_NODES + dst;
  int slot = atomicAdd(&cursor[rowg], 1);
  if (slot < CAP) rec[(size_t)rowg * CAP + slot] = make_int2(src, __float_as_int(sc));
}

__global__ void sin_kernel(const int* __restrict__ cursor, float* __restrict__ s_in) {
  int i = blockIdx.x * blockDim.x + threadIdx.x;
  if (i >= NROWS) return;
  s_in[i] = rsqrtf(fmaxf((float)cursor[i], 1.0f));
}

// emb fp32 -> bf16 (4 elems/thread); also Wt transpose + bmean in low threads
__global__ void prep_kernel(const float* __restrict__ emb, const float* __restrict__ W,
                            const float* __restrict__ biases,
                            unsigned short* __restrict__ hb, unsigned short* __restrict__ Wt,
                            float* __restrict__ bmean) {
  int t = blockIdx.x * blockDim.x + threadIdx.x;
  if (t < N_NODES * D / 4) {
    f32x4 v = *(const f32x4*)(emb + (size_t)t * 4);
    u16x4 o;
#pragma unroll
    for (int j = 0; j < 4; ++j) o[j] = f2bf(v[j]);
    *(u16x4*)(hb + (size_t)t * 4) = o;
  }
  if (t < LAYERS * R * D * D) {
    int k = t & 127;
    int c = (t >> 7) & 127;
    int lr = t >> 14;
    Wt[((size_t)lr << 14) | (c << 7) | k] = f2bf(W[((size_t)lr << 14) | (k << 7) | c]);
  }
  if (t < LAYERS * D) {
    int l = t >> 7, cc = t & 127;
    float s = 0.f;
    for (int r = 0; r < R; ++r) s += biases[((size_t)l * R + r) * D + cc];
    bmean[t] = s * 0.25f;
  }
}

// ================= fused gather-aggregate -> MFMA GEMM -> epilogue ==========
// One block per 16 dst nodes. Phase 1 (wave w = relation w): branchless
// 4-edge gather (pads contribute sc=0), masked tail for rare n>4. Lane
// (m,q) accumulates exactly its A-fragment slots so LDS traffic is
// lane-consecutive b128 (conflict-free). Phase 2: wave w computes cols
// [w*32, w*32+32) over all 4 relations.
__global__ __launch_bounds__(256) void fused_kernel(
    const unsigned short* __restrict__ hb,     // [N][128] bf16
    const int2* __restrict__ rec,              // [NROWS][CAP] {src, s_out}, zero-padded
    const int* __restrict__ cnt,               // [NROWS] in-degree
    const float* __restrict__ s_in,            // [NROWS]
    const unsigned short* __restrict__ Wt,     // layer: [R][128 col][128 k] bf16
    const float* __restrict__ bmean,           // [128]
    const unsigned short* __restrict__ resid_bf,  // bf16 residual or null
    float* __restrict__ out_f,                 // fp32 out (final layer) or null
    unsigned short* __restrict__ out_bf) {     // bf16 out (hidden layer) or null
  __shared__ unsigned short t_lds[R * 4 * 64 * 8];  // 16 KB, fragment order
  const int w = threadIdx.x >> 6;
  const int lane = threadIdx.x & 63;
  const int m = lane & 15;
  const int q = lane >> 4;
  const int row0 = blockIdx.x * 16;

  // ---- phase 1: branchless gather-aggregate ----
  {
    const int r = w;
    const int rowg = r * N_NODES + row0 + m;
    const int2* rp = rec + (size_t)rowg * CAP;
    int n = cnt[rowg];                      // loads concurrently with rec/h
    n = (n > CAP) ? CAP : n;
    // unconditional: records 0..3 (covers 98.1% of rows fully; pads are sc=0)
    i32x4 r01 = *(const i32x4*)(rp);
    i32x4 r23 = *(const i32x4*)(rp + 2);
    int   srcs[4] = { r01.x, r01.z, r23.x, r23.z };
    float scs[4]  = { __int_as_float(r01.y), __int_as_float(r01.w),
                      __int_as_float(r23.y), __int_as_float(r23.w) };
    bf16x8 av[4][4];
#pragma unroll
    for (int e = 0; e < 4; ++e) {
      const unsigned short* hp = hb + (size_t)srcs[e] * D + q * 8;
#pragma unroll
      for (int ks = 0; ks < 4; ++ks) av[e][ks] = *(const bf16x8*)(hp + ks * 32);
    }
    float accf[4][8];
#pragma unroll
    for (int ks = 0; ks < 4; ++ks)
#pragma unroll
      for (int j = 0; j < 8; ++j) accf[ks][j] = 0.f;
#pragma unroll
    for (int e = 0; e < 4; ++e)
#pragma unroll
      for (int ks = 0; ks < 4; ++ks)
#pragma unroll
        for (int j = 0; j < 8; ++j)
          accf[ks][j] += scs[e] * bf2f((unsigned short)av[e][ks][j]);

    // rare tail (n > 4); i is always even, slots i,i+1 valid (pads sc=0)
    for (int i = 4; i < n; i += 2) {
      i32x4 rr = *(const i32x4*)(rp + i);
      float c0 = __int_as_float(rr.y), c1 = __int_as_float(rr.w);
      const unsigned short* h0 = hb + (size_t)rr.x * D + q * 8;
      const unsigned short* h1 = hb + (size_t)rr.z * D + q * 8;
#pragma unroll
      for (int ks = 0; ks < 4; ++ks) {
        bf16x8 a0 = *(const bf16x8*)(h0 + ks * 32);
        bf16x8 a1 = *(const bf16x8*)(h1 + ks * 32);
#pragma unroll
        for (int j = 0; j < 8; ++j)
          accf[ks][j] += c0 * bf2f((unsigned short)a0[j]) + c1 * bf2f((unsigned short)a1[j]);
      }
    }
#pragma unroll
    for (int ks = 0; ks < 4; ++ks) {
      union { bf16x8 v; unsigned short s[8]; } u;
#pragma unroll
      for (int j = 0; j < 8; ++j) u.s[j] = f2bf(accf[ks][j]);
      *(bf16x8*)&t_lds[(((r * 4 + ks) << 6) + lane) * 8] = u.v;
    }
  }
  __syncthreads();

  // ---- phase 2: GEMM + epilogue ----
  float oacc[2][4];
#pragma unroll
  for (int c = 0; c < 2; ++c)
#pragma unroll
    for (int i = 0; i < 4; ++i) oacc[c][i] = 0.f;

  for (int r = 0; r < R; ++r) {
    f32x4 acc2[2];
#pragma unroll
    for (int c = 0; c < 2; ++c) acc2[c] = (f32x4){0.f, 0.f, 0.f, 0.f};
    const unsigned short* wr = Wt + ((size_t)r << 14);
#pragma unroll
    for (int ks = 0; ks < 4; ++ks) {
      bf16x8 a = *(const bf16x8*)&t_lds[(((r * 4 + ks) << 6) + lane) * 8];
#pragma unroll
      for (int c = 0; c < 2; ++c) {
        int ct = w * 2 + c;
        const unsigned short* bp = wr + ((ct * 16 + m) << 7) + ks * 32 + q * 8;
        bf16x8 b = *(const bf16x8*)bp;
        acc2[c] = __builtin_amdgcn_mfma_f32_16x16x32_bf16(a, b, acc2[c], 0, 0, 0);
      }
    }
    f32x4 s = *(const f32x4*)(s_in + (size_t)r * N_NODES + row0 + q * 4);
#pragma unroll
    for (int c = 0; c < 2; ++c)
#pragma unroll
      for (int i = 0; i < 4; ++i) oacc[c][i] += s[i] * acc2[c][i];
  }

#pragma unroll
  for (int c = 0; c < 2; ++c) {
    int colx = (w * 2 + c) * 16 + m;
    float bm = bmean[colx];
#pragma unroll
    for (int i = 0; i < 4; ++i) {
      int row = row0 + q * 4 + i;
      float v = oacc[c][i] * 0.25f + bm;
      v = (v >= 0.f) ? v : 0.2f * v;
      if (resid_bf) v += bf2f(resid_bf[(size_t)row * D + colx]);
      if (out_f) out_f[(size_t)row * D + colx] = v;
      else       out_bf[(size_t)row * D + colx] = f2bf(v);
    }
  }
}

extern "C" void kernel_launch(void* const* d_in, const int* in_sizes, int n_in,
                              void* d_out, int out_size, void* d_ws, size_t ws_size,
                              hipStream_t stream) {
  const float* emb    = (const float*)d_in[0];
  const float* W      = (const float*)d_in[1];
  const float* biases = (const float*)d_in[2];
  const int*   edges  = (const int*)d_in[3];
  float* out = (float*)d_out;
  char* ws = (char*)d_ws;

  size_t off = 0;
  auto alloc = [&](size_t bytes) { size_t o = off; off += (bytes + 255) & ~255ull; return o; };
  // ints + rec contiguous at ws start -> single zeroing memset
  int* ints      = (int*)(ws + alloc((size_t)2 * NROWS * 4));   // [deg_i | cursor]
  int* deg_i     = ints;
  int* cursor    = ints + NROWS;
  int2* rec      = (int2*)(ws + alloc((size_t)NROWS * CAP * 8));   // 51.2 MB
  size_t zero_bytes = off;                                         // memset range
  float* s_out   = (float*)(ws + alloc((size_t)NROWS * 4));
  float* s_in    = (float*)(ws + alloc((size_t)NROWS * 4));
  unsigned short* hb  = (unsigned short*)(ws + alloc((size_t)N_NODES * D * 2));
  unsigned short* hb2 = (unsigned short*)(ws + alloc((size_t)N_NODES * D * 2));
  unsigned short* Wt  = (unsigned short*)(ws + alloc((size_t)LAYERS * R * D * D * 2));
  float* bmean   = (float*)(ws + alloc((size_t)LAYERS * D * 4));
  (void)ws_size;

  // ---- prep (edges fixed across layers; padded rows, no scan) ----
  hipMemsetAsync(ws, 0, zero_bytes, stream);
  count_kernel<<<dim3((NE + 255) / 256, R), 256, 0, stream>>>(edges, deg_i);
  sout_kernel<<<(NROWS + 255) / 256, 256, 0, stream>>>(deg_i, s_out);
  fill_kernel<<<dim3((NE + 255) / 256, R), 256, 0, stream>>>(edges, s_out, cursor, rec);
  sin_kernel<<<(NROWS + 255) / 256, 256, 0, stream>>>(cursor, s_in);
  prep_kernel<<<(N_NODES * D / 4 + 255) / 256, 256, 0, stream>>>(emb, W, biases, hb, Wt, bmean);

  const int fused_blocks = N_NODES / 16;  // 6250

  // layer 0: emb(bf16) -> hb2(bf16), no residual
  fused_kernel<<<fused_blocks, 256, 0, stream>>>(
      hb, rec, cursor, s_in, Wt, bmean, nullptr, nullptr, hb2);
  // layer 1: hb2 -> out(fp32), residual = hb2
  fused_kernel<<<fused_blocks, 256, 0, stream>>>(
      hb2, rec, cursor, s_in, Wt + (size_t)R * D * D, bmean + D, hb2, out, nullptr);
}

// Round 6
// 334.364 us; speedup vs baseline: 1.3523x; 1.3523x over previous
//
#include <hip/hip_runtime.h>
#include <cstdint>
#include <cstddef>

#define N_NODES 100000
#define D 128
#define R 4
#define NE 150000
#define LAYERS 2
#define NROWS (R * N_NODES)   // 400000
#define CAP 16                // max in-degree per (rel,dst); Poisson(1.5) -> P(>16) ~ 1e-12
#define TILES (N_NODES / 16)  // 6250
#define GRID 256              // persistent: one block per CU
#define TPB 512               // 8 waves: 4 producers + 4 consumers

typedef __attribute__((ext_vector_type(8))) short bf16x8;
typedef __attribute__((ext_vector_type(4))) float f32x4;
typedef __attribute__((ext_vector_type(4))) int i32x4;
typedef __attribute__((ext_vector_type(4))) unsigned short u16x4;

__device__ __forceinline__ unsigned short f2bf(float x) {
  union { float f; unsigned int u; } v; v.f = x;
  unsigned int u = v.u;
  return (unsigned short)((u + 0x7fffu + ((u >> 16) & 1u)) >> 16);  // RNE
}
__device__ __forceinline__ float bf2f(unsigned short u) {
  union { unsigned int i; float f; } v; v.i = ((unsigned int)u) << 16;
  return v.f;
}

// ---- count out-degree (int atomics); deg_i pre-zeroed ----
__global__ void count_kernel(const int* __restrict__ edges, int* __restrict__ deg_i) {
  int e = blockIdx.x * blockDim.x + threadIdx.x;
  int r = blockIdx.y;
  if (e >= NE) return;
  int src = edges[(size_t)(r * 2) * NE + e];
  atomicAdd(&deg_i[r * N_NODES + src], 1);
}

// fill padded edge records {src, rsqrt(deg_out[src])}; cursor counts in-degree.
// rec pre-zeroed -> pad slots contribute sc=0.
__global__ void fill_kernel(const int* __restrict__ edges, const int* __restrict__ deg_i,
                            int* __restrict__ cursor, int2* __restrict__ rec) {
  int e = blockIdx.x * blockDim.x + threadIdx.x;
  int r = blockIdx.y;
  if (e >= NE) return;
  int src = edges[(size_t)(r * 2) * NE + e];
  int dst = edges[(size_t)(r * 2 + 1) * NE + e];
  float sc = rsqrtf(fmaxf((float)deg_i[r * N_NODES + src], 1.0f));
  int rowg = r * N_NODES + dst;
  int slot = atomicAdd(&cursor[rowg], 1);
  if (slot < CAP) rec[(size_t)rowg * CAP + slot] = make_int2(src, __float_as_int(sc));
}

// emb fp32 -> bf16; Wt transpose; bmean; s_in from cursor (runs AFTER fill)
__global__ void prep_kernel(const float* __restrict__ emb, const float* __restrict__ W,
                            const float* __restrict__ biases, const int* __restrict__ cursor,
                            unsigned short* __restrict__ hb, unsigned short* __restrict__ Wt,
                            float* __restrict__ bmean, float* __restrict__ s_in) {
  int t = blockIdx.x * blockDim.x + threadIdx.x;
  if (t < N_NODES * D / 4) {
    f32x4 v = *(const f32x4*)(emb + (size_t)t * 4);
    u16x4 o;
#pragma unroll
    for (int j = 0; j < 4; ++j) o[j] = f2bf(v[j]);
    *(u16x4*)(hb + (size_t)t * 4) = o;
  }
  if (t < LAYERS * R * D * D) {
    int k = t & 127;
    int c = (t >> 7) & 127;
    int lr = t >> 14;
    Wt[((size_t)lr << 14) | (c << 7) | k] = f2bf(W[((size_t)lr << 14) | (k << 7) | c]);
  }
  if (t < NROWS) s_in[t] = rsqrtf(fmaxf((float)cursor[t], 1.0f));
  if (t < LAYERS * D) {
    int l = t >> 7, cc = t & 127;
    float s = 0.f;
    for (int r = 0; r < R; ++r) s += biases[((size_t)l * R + r) * D + cc];
    bmean[t] = s * 0.25f;
  }
}

// ======== persistent producer/consumer fused kernel =========================
// 256 blocks x 8 waves. Waves 0-3: gather-aggregate relation w of tile it into
// t_lds[it&1]. Waves 4-7: MFMA+epilogue of tile it-1 from t_lds[(it-1)&1],
// B-fragments held in registers (loaded once). One barrier per tile.
__global__ __launch_bounds__(TPB, 2) void fused_kernel(
    const unsigned short* __restrict__ hb,     // [N][128] bf16
    const int2* __restrict__ rec,              // [NROWS][CAP] {src, s_out}, zero-padded
    const int* __restrict__ cnt,               // [NROWS] in-degree (may exceed CAP)
    const float* __restrict__ s_in,            // [NROWS]
    const unsigned short* __restrict__ Wt,     // layer: [R][128 col][128 k] bf16
    const float* __restrict__ bmean,           // [128]
    const unsigned short* __restrict__ resid_bf,
    float* __restrict__ out_f,
    unsigned short* __restrict__ out_bf) {
  __shared__ unsigned short t_lds[2][R * 4 * 64 * 8];  // 2 x 16 KB
  const int w = threadIdx.x >> 6;
  const int lane = threadIdx.x & 63;
  const int m = lane & 15;
  const int q = lane >> 4;
  const int bid = blockIdx.x;
  const int nt = (TILES - bid + GRID - 1) / GRID;   // tiles for this block

  if (w < 4) {
    // -------------------- producer: relation w --------------------
    const int r = w;
    for (int it = 0; it < nt + 1; ++it) {
      if (it < nt) {
        const int tile = bid + it * GRID;
        const int rowg = r * N_NODES + tile * 16 + m;
        const int2* rp = rec + (size_t)rowg * CAP;
        int n = cnt[rowg];
        n = (n > CAP) ? CAP : n;
        i32x4 r01 = *(const i32x4*)(rp);
        i32x4 r23 = *(const i32x4*)(rp + 2);
        int   srcs[4] = { r01.x, r01.z, r23.x, r23.z };
        float scs[4]  = { __int_as_float(r01.y), __int_as_float(r01.w),
                          __int_as_float(r23.y), __int_as_float(r23.w) };
        float accf[4][8];
#pragma unroll
        for (int ks = 0; ks < 4; ++ks)
#pragma unroll
          for (int j = 0; j < 8; ++j) accf[ks][j] = 0.f;
#pragma unroll
        for (int e = 0; e < 4; ++e) {
          const unsigned short* hp = hb + (size_t)srcs[e] * D + q * 8;
#pragma unroll
          for (int ks = 0; ks < 4; ++ks) {
            bf16x8 a = *(const bf16x8*)(hp + ks * 32);
#pragma unroll
            for (int j = 0; j < 8; ++j)
              accf[ks][j] += scs[e] * bf2f((unsigned short)a[j]);
          }
        }
        for (int i = 4; i < n; i += 2) {   // rare tail (pads sc=0)
          i32x4 rr = *(const i32x4*)(rp + i);
          float c0 = __int_as_float(rr.y), c1 = __int_as_float(rr.w);
          const unsigned short* h0 = hb + (size_t)rr.x * D + q * 8;
          const unsigned short* h1 = hb + (size_t)rr.z * D + q * 8;
#pragma unroll
          for (int ks = 0; ks < 4; ++ks) {
            bf16x8 a0 = *(const bf16x8*)(h0 + ks * 32);
            bf16x8 a1 = *(const bf16x8*)(h1 + ks * 32);
#pragma unroll
            for (int j = 0; j < 8; ++j)
              accf[ks][j] += c0 * bf2f((unsigned short)a0[j]) + c1 * bf2f((unsigned short)a1[j]);
          }
        }
        unsigned short* dstp = &t_lds[it & 1][(((r * 4) << 6) + lane) * 8];
#pragma unroll
        for (int ks = 0; ks < 4; ++ks) {
          union { bf16x8 v; unsigned short s[8]; } u;
#pragma unroll
          for (int j = 0; j < 8; ++j) u.s[j] = f2bf(accf[ks][j]);
          *(bf16x8*)(dstp + (ks << 6) * 8) = u.v;
        }
      }
      __syncthreads();
    }
  } else {
    // -------------------- consumer: cols [cw*32, cw*32+32) --------------------
    const int cw = w - 4;
    bf16x8 breg[R][4][2];
#pragma unroll
    for (int r = 0; r < R; ++r) {
      const unsigned short* wr = Wt + ((size_t)r << 14);
#pragma unroll
      for (int ks = 0; ks < 4; ++ks)
#pragma unroll
        for (int c = 0; c < 2; ++c) {
          int ct = cw * 2 + c;
          breg[r][ks][c] = *(const bf16x8*)(wr + ((ct * 16 + m) << 7) + ks * 32 + q * 8);
        }
    }
    for (int it = 0; it < nt + 1; ++it) {
      if (it > 0) {
        const int tile = bid + (it - 1) * GRID;
        const int pb = (it - 1) & 1;
        float oacc[2][4];
#pragma unroll
        for (int c = 0; c < 2; ++c)
#pragma unroll
          for (int i = 0; i < 4; ++i) oacc[c][i] = 0.f;
#pragma unroll
        for (int r = 0; r < R; ++r) {
          f32x4 acc2[2];
#pragma unroll
          for (int c = 0; c < 2; ++c) acc2[c] = (f32x4){0.f, 0.f, 0.f, 0.f};
#pragma unroll
          for (int ks = 0; ks < 4; ++ks) {
            bf16x8 a = *(const bf16x8*)&t_lds[pb][(((r * 4 + ks) << 6) + lane) * 8];
#pragma unroll
            for (int c = 0; c < 2; ++c)
              acc2[c] = __builtin_amdgcn_mfma_f32_16x16x32_bf16(a, breg[r][ks][c], acc2[c], 0, 0, 0);
          }
          f32x4 s = *(const f32x4*)(s_in + (size_t)r * N_NODES + tile * 16 + q * 4);
#pragma unroll
          for (int c = 0; c < 2; ++c)
#pragma unroll
            for (int i = 0; i < 4; ++i) oacc[c][i] += s[i] * acc2[c][i];
        }
#pragma unroll
        for (int c = 0; c < 2; ++c) {
          int colx = (cw * 2 + c) * 16 + m;
          float bm = bmean[colx];
#pragma unroll
          for (int i = 0; i < 4; ++i) {
            int row = tile * 16 + q * 4 + i;
            float v = oacc[c][i] * 0.25f + bm;
            v = (v >= 0.f) ? v : 0.2f * v;
            if (resid_bf) v += bf2f(resid_bf[(size_t)row * D + colx]);
            if (out_f) out_f[(size_t)row * D + colx] = v;
            else       out_bf[(size_t)row * D + colx] = f2bf(v);
          }
        }
      }
      __syncthreads();
    }
  }
}

extern "C" void kernel_launch(void* const* d_in, const int* in_sizes, int n_in,
                              void* d_out, int out_size, void* d_ws, size_t ws_size,
                              hipStream_t stream) {
  const float* emb    = (const float*)d_in[0];
  const float* W      = (const float*)d_in[1];
  const float* biases = (const float*)d_in[2];
  const int*   edges  = (const int*)d_in[3];
  float* out = (float*)d_out;
  char* ws = (char*)d_ws;

  size_t off = 0;
  auto alloc = [&](size_t bytes) { size_t o = off; off += (bytes + 255) & ~255ull; return o; };
  // ints + rec contiguous at ws start -> single zeroing memset
  int* ints      = (int*)(ws + alloc((size_t)2 * NROWS * 4));   // [deg_i | cursor]
  int* deg_i     = ints;
  int* cursor    = ints + NROWS;
  int2* rec      = (int2*)(ws + alloc((size_t)NROWS * CAP * 8));   // 51.2 MB
  size_t zero_bytes = off;
  float* s_in    = (float*)(ws + alloc((size_t)NROWS * 4));
  unsigned short* hb  = (unsigned short*)(ws + alloc((size_t)N_NODES * D * 2));
  unsigned short* hb2 = (unsigned short*)(ws + alloc((size_t)N_NODES * D * 2));
  unsigned short* Wt  = (unsigned short*)(ws + alloc((size_t)LAYERS * R * D * D * 2));
  float* bmean   = (float*)(ws + alloc((size_t)LAYERS * D * 4));
  (void)ws_size;

  // ---- prep: memset -> count -> fill -> prep (4 dispatches) ----
  hipMemsetAsync(ws, 0, zero_bytes, stream);
  count_kernel<<<dim3((NE + 255) / 256, R), 256, 0, stream>>>(edges, deg_i);
  fill_kernel<<<dim3((NE + 255) / 256, R), 256, 0, stream>>>(edges, deg_i, cursor, rec);
  prep_kernel<<<(N_NODES * D / 4 + 255) / 256, 256, 0, stream>>>(
      emb, W, biases, cursor, hb, Wt, bmean, s_in);

  // layer 0: emb(bf16) -> hb2(bf16), no residual
  fused_kernel<<<GRID, TPB, 0, stream>>>(
      hb, rec, cursor, s_in, Wt, bmean, nullptr, nullptr, hb2);
  // layer 1: hb2 -> out(fp32), residual = hb2
  fused_kernel<<<GRID, TPB, 0, stream>>>(
      hb2, rec, cursor, s_in, Wt + (size_t)R * D * D, bmean + D, hb2, out, nullptr);
}